// Round 1
// baseline (110.926 us; speedup 1.0000x reference)
//
#include <hip/hip_runtime.h>
#include <hip/hip_bf16.h>

#define LOG2PI_F 1.8378770664093453f
#define LOG2E_F  1.4426950408889634f
#define LN2_F    0.6931471805599453f

// Precompute per-(k,d) affine coefficients of lp_k in (Ez, Ez2), pre-scaled
// by log2(e) so the main loop can use v_exp_f32 (2^x) directly.
// coef layout: [d][k] float4 {A2, B2, C2, 0} -> contiguous in k for scalar
// (s_load) streaming with wave-uniform d.
__global__ __launch_bounds__(256) void coef_kernel(
    const float* __restrict__ means, const float* __restrict__ log_vars,
    const float* __restrict__ w, float4* __restrict__ coef)
{
    __shared__ float red[256];
    const int t = threadIdx.x;   // k
    const int d = blockIdx.x;    // 0..127

    // log_softmax(w) over K=256, computed redundantly per block (cheap)
    float wv = w[t];
    red[t] = wv; __syncthreads();
    for (int off = 128; off > 0; off >>= 1) {
        if (t < off) red[t] = fmaxf(red[t], red[t + off]);
        __syncthreads();
    }
    float m = red[0]; __syncthreads();
    red[t] = expf(wv - m); __syncthreads();
    for (int off = 128; off > 0; off >>= 1) {
        if (t < off) red[t] += red[t + off];
        __syncthreads();
    }
    float logw = wv - m - logf(red[0]);

    const int idx = t * 128 + d;          // [k][d]
    float mu = means[idx];
    float lv = log_vars[idx];
    float p  = expf(-lv);
    float A = -0.5f * (LOG2PI_F + lv) - 0.5f * p * mu * mu + logw;
    float B = p * mu;
    float C = -0.5f * p;
    coef[d * 256 + t] = make_float4(A * LOG2E_F, B * LOG2E_F, C * LOG2E_F, 0.f);
}

// Fused: reduce z over MC (coalesced), LDS-transpose to d-per-wave layout,
// 256-component logsumexp with scalar coefficient stream, transpose back.
__global__ __launch_bounds__(1024, 8) void mog_kernel(
    const float* __restrict__ z, const float4* __restrict__ coef,
    float* __restrict__ out)
{
    // [16 d][64 b + pad] of (x=Ez, y=Ez2); reused for output staging
    __shared__ float2 xy[16][65];

    const int t  = threadIdx.x;
    const int b0 = blockIdx.x << 6;   // 64 b per block   (gridDim.x = 64)
    const int d0 = blockIdx.y << 4;   // 16 d per block   (gridDim.y = 8)

    // ---- phase 1: Ez / Ez2, coalesced over (b,d) ----
    const int dl = t & 15, bl = t >> 4;
    const int base = (b0 + bl) * 128 + d0 + dl;
    float s1 = 0.f, s2 = 0.f;
    #pragma unroll
    for (int mc = 0; mc < 16; ++mc) {
        float v = z[base + mc * 524288];
        s1 += v;
        s2 = fmaf(v, v, s2);
    }
    xy[dl][bl] = make_float2(s1 * 0.0625f, s2 * 0.0625f);
    __syncthreads();

    // ---- phase 2: wave w owns d = d0+w (uniform); lane l owns b = b0+l ----
    const int wv = t >> 6;
    const int l  = t & 63;
    float2 v2 = xy[wv][l];
    const float x = v2.x, y = v2.y;

    const int d = __builtin_amdgcn_readfirstlane(d0 + wv);
    const float4* __restrict__ cp = coef + ((size_t)d << 8);

    float sA = 0.f, sB = 0.f;
    #pragma unroll 4
    for (int k = 0; k < 256; k += 2) {
        float4 c0 = cp[k];
        float4 c1 = cp[k + 1];
        float t0 = fmaf(c0.y, x, c0.x);
        t0 = fmaf(c0.z, y, t0);
        float t1 = fmaf(c1.y, x, c1.x);
        t1 = fmaf(c1.z, y, t1);
        sA += __builtin_amdgcn_exp2f(t0);
        sB += __builtin_amdgcn_exp2f(t1);
    }
    float res = LN2_F * __builtin_amdgcn_logf(sA + sB);

    // ---- transpose back through LDS, coalesced store ----
    __syncthreads();
    float* os = (float*)&xy[0][0];     // rows of 130 floats
    os[wv * 130 + l] = res;
    __syncthreads();
    out[base] = os[dl * 130 + bl];
}

extern "C" void kernel_launch(void* const* d_in, const int* in_sizes, int n_in,
                              void* d_out, int out_size, void* d_ws, size_t ws_size,
                              hipStream_t stream) {
    const float* z        = (const float*)d_in[0];
    const float* means    = (const float*)d_in[1];
    const float* log_vars = (const float*)d_in[2];
    const float* w        = (const float*)d_in[3];
    float* out  = (float*)d_out;
    float4* coef = (float4*)d_ws;   // 128*256*16 B = 512 KiB

    coef_kernel<<<128, 256, 0, stream>>>(means, log_vars, w, coef);
    mog_kernel<<<dim3(64, 8), 1024, 0, stream>>>(z, coef, out);
}

// Round 2
// 102.969 us; speedup vs baseline: 1.0773x; 1.0773x over previous
//
#include <hip/hip_runtime.h>
#include <hip/hip_bf16.h>

#define LOG2PI_F 1.8378770664093453f
#define LOG2E_F  1.4426950408889634f
#define LN2_F    0.6931471805599453f

// Precompute per-(k,d) affine coefficients of lp_k in (Ez, Ez2), pre-scaled
// by log2(e) so the main loop uses raw v_exp_f32 (2^x).
// coef layout: [d][k] float4 {A2, B2, C2, 0}, contiguous in k.
__global__ __launch_bounds__(256) void coef_kernel(
    const float* __restrict__ means, const float* __restrict__ log_vars,
    const float* __restrict__ w, float4* __restrict__ coef)
{
    __shared__ float red[256];
    const int t = threadIdx.x;   // k
    const int d = blockIdx.x;    // 0..127

    // log_softmax(w) over K=256, redundant per block (cheap)
    float wv = w[t];
    red[t] = wv; __syncthreads();
    for (int off = 128; off > 0; off >>= 1) {
        if (t < off) red[t] = fmaxf(red[t], red[t + off]);
        __syncthreads();
    }
    float m = red[0]; __syncthreads();
    red[t] = expf(wv - m); __syncthreads();
    for (int off = 128; off > 0; off >>= 1) {
        if (t < off) red[t] += red[t + off];
        __syncthreads();
    }
    float logw = wv - m - logf(red[0]);

    const int idx = t * 128 + d;          // [k][d]
    float mu = means[idx];
    float lv = log_vars[idx];
    float p  = expf(-lv);
    float A = -0.5f * (LOG2PI_F + lv) - 0.5f * p * mu * mu + logw;
    float B = p * mu;
    float C = -0.5f * p;
    coef[d * 256 + t] = make_float4(A * LOG2E_F, B * LOG2E_F, C * LOG2E_F, 0.f);
}

// Block tile: 4 d x 256 b, 256 threads (4 waves). Wave w owns d = d0+w
// (uniform -> LDS coefficient reads broadcast); lane owns 4 b values so one
// ds_read_b128 feeds 4 exps (trans pipe is the floor, not DS return bus).
__global__ __launch_bounds__(256, 4) void mog_kernel(
    const float* __restrict__ z, const float4* __restrict__ coefg,
    float* __restrict__ out)
{
    __shared__ float4 cf[4 * 256];      // 16 KB   [d_local][k]
    __shared__ float2 xy[4][258];       // ~8.3 KB (Ez, Ez2), padded
    __shared__ float  res[4][260];      // ~4.2 KB outputs, padded

    const int t  = threadIdx.x;
    const int b0 = blockIdx.x << 8;     // 256 b per block (grid.x = 16)
    const int d0 = blockIdx.y << 2;     // 4 d per block   (grid.y = 32)

    // ---- stage coefficients: 1024 float4, coalesced ----
    {
        const float4* g = coefg + ((size_t)d0 << 8);
        #pragma unroll
        for (int i = 0; i < 4; ++i) cf[t + i * 256] = g[t + i * 256];
    }

    // ---- phase 1: Ez / Ez2 (float2 loads: 2 d per thread) ----
    {
        const int dl2 = (t & 1) << 1;       // 0 or 2
        const int bl  = t >> 1;             // [0,128)
        #pragma unroll
        for (int j = 0; j < 2; ++j) {
            const int b = bl + (j << 7);
            const float* zp = z + (size_t)(b0 + b) * 128 + d0 + dl2;
            float s1x = 0.f, s1y = 0.f, s2x = 0.f, s2y = 0.f;
            #pragma unroll
            for (int mc = 0; mc < 16; ++mc) {
                float2 v = *(const float2*)(zp + (size_t)mc * 524288);
                s1x += v.x; s2x = fmaf(v.x, v.x, s2x);
                s1y += v.y; s2y = fmaf(v.y, v.y, s2y);
            }
            xy[dl2][b]     = make_float2(s1x * 0.0625f, s2x * 0.0625f);
            xy[dl2 + 1][b] = make_float2(s1y * 0.0625f, s2y * 0.0625f);
        }
    }
    __syncthreads();

    // ---- phase 2: wave-uniform d, 4 b per lane ----
    {
        const int w = t >> 6;               // d_local, wave-uniform
        const int l = t & 63;
        const float4* cw = cf + (w << 8);
        float x0, x1, x2, x3, y0, y1, y2, y3;
        { float2 v = xy[w][l];       x0 = v.x; y0 = v.y; }
        { float2 v = xy[w][l +  64]; x1 = v.x; y1 = v.y; }
        { float2 v = xy[w][l + 128]; x2 = v.x; y2 = v.y; }
        { float2 v = xy[w][l + 192]; x3 = v.x; y3 = v.y; }

        float a0 = 0.f, a1 = 0.f, a2 = 0.f, a3 = 0.f;
        #pragma unroll 4
        for (int k = 0; k < 256; ++k) {
            float4 c = cw[k];
            float t0 = fmaf(c.z, y0, fmaf(c.y, x0, c.x));
            float t1 = fmaf(c.z, y1, fmaf(c.y, x1, c.x));
            float t2 = fmaf(c.z, y2, fmaf(c.y, x2, c.x));
            float t3 = fmaf(c.z, y3, fmaf(c.y, x3, c.x));
            a0 += __builtin_amdgcn_exp2f(t0);
            a1 += __builtin_amdgcn_exp2f(t1);
            a2 += __builtin_amdgcn_exp2f(t2);
            a3 += __builtin_amdgcn_exp2f(t3);
        }
        res[w][l]       = LN2_F * __builtin_amdgcn_logf(a0);
        res[w][l +  64] = LN2_F * __builtin_amdgcn_logf(a1);
        res[w][l + 128] = LN2_F * __builtin_amdgcn_logf(a2);
        res[w][l + 192] = LN2_F * __builtin_amdgcn_logf(a3);
    }
    __syncthreads();

    // ---- phase 3: transposed coalesced writeout ----
    {
        const int dl = t & 3;
        const int bl = t >> 2;              // [0,64)
        #pragma unroll
        for (int j = 0; j < 4; ++j) {
            const int b = bl + (j << 6);
            out[(size_t)(b0 + b) * 128 + d0 + dl] = res[dl][b];
        }
    }
}

extern "C" void kernel_launch(void* const* d_in, const int* in_sizes, int n_in,
                              void* d_out, int out_size, void* d_ws, size_t ws_size,
                              hipStream_t stream) {
    const float* z        = (const float*)d_in[0];
    const float* means    = (const float*)d_in[1];
    const float* log_vars = (const float*)d_in[2];
    const float* w        = (const float*)d_in[3];
    float* out   = (float*)d_out;
    float4* coef = (float4*)d_ws;   // 128*256*16 B = 512 KiB

    coef_kernel<<<128, 256, 0, stream>>>(means, log_vars, w, coef);
    mog_kernel<<<dim3(16, 32), 256, 0, stream>>>(z, coef, out);
}